// Round 4
// baseline (278.736 us; speedup 1.0000x reference)
//
#include <hip/hip_runtime.h>

#define M_ROWS 12608          // 64*197
#define K_DIM  768
#define QSZ    9682944        // 64*12*197*64 elements per q/k plane
#define VTSZ   10223616       // 768 heads * 64 d * 208 kt (zero-ish padded tail)
#define XB_ELEMS 9732096      // 12672*768 bf16 X copy (lives in d_out scratch)

typedef __bf16 bf16x8 __attribute__((ext_vector_type(8)));
typedef float  f32x4  __attribute__((ext_vector_type(4)));

__device__ __forceinline__ unsigned short f2bf(float f) {
    unsigned u = __builtin_bit_cast(unsigned, f);
    u += 0x7fffu + ((u >> 16) & 1u);          // RNE, inputs are finite
    return (unsigned short)(u >> 16);
}

__device__ __forceinline__ void gll16(const unsigned short* g, unsigned short* l) {
    __builtin_amdgcn_global_load_lds(
        (const __attribute__((address_space(1))) unsigned int*)g,
        (__attribute__((address_space(3))) unsigned int*)l, 16, 0, 0);
}

// ---------------- Kernel 0: X fp32 -> bf16 (stored in d_out scratch area) ----------------
__global__ void x2bf_kernel(const float* __restrict__ X, unsigned short* __restrict__ Xb) {
    size_t base = ((size_t)blockIdx.x * 256 + threadIdx.x) * 8;
    float4 a = *(const float4*)(X + base);
    float4 b = *(const float4*)(X + base + 4);
    ushort4 lo, hi;
    lo.x = f2bf(a.x); lo.y = f2bf(a.y); lo.z = f2bf(a.z); lo.w = f2bf(a.w);
    hi.x = f2bf(b.x); hi.y = f2bf(b.y); hi.z = f2bf(b.z); hi.w = f2bf(b.w);
    *(ushort4*)(Xb + base) = lo;
    *(ushort4*)(Xb + base + 4) = hi;
}

// ---------------- Kernel 1: W [768,2304] fp32 -> Wt [2304,768] bf16 ----------------
__global__ void wtrans_kernel(const float* __restrict__ W, unsigned short* __restrict__ Wt) {
    __shared__ float tile[32][33];
    int n0 = blockIdx.x * 32, k0 = blockIdx.y * 32;
    int tx = threadIdx.x, ty = threadIdx.y;
#pragma unroll
    for (int i = 0; i < 4; ++i)
        tile[ty + i * 8][tx] = W[(size_t)(k0 + ty + i * 8) * 2304 + n0 + tx];
    __syncthreads();
#pragma unroll
    for (int i = 0; i < 4; ++i)
        Wt[(size_t)(n0 + ty + i * 8) * K_DIM + k0 + tx] = f2bf(tile[tx][ty + i * 8]);
}

// ---------------- Kernel 2: QKV GEMM, global_load_lds staging, k-major LDS ----------------
__global__ __launch_bounds__(256, 2) void qkv_gemm_kernel(
        const unsigned short* __restrict__ Xb, const unsigned short* __restrict__ Wt,
        const float* __restrict__ bias, unsigned short* __restrict__ qkv) {
    __shared__ __align__(16) unsigned short As[4096];   // 8 KB
    __shared__ __align__(16) unsigned short Bs[4096];   // 8 KB

    const int m0 = blockIdx.y * 128, n0 = blockIdx.x * 128;
    const int t = threadIdx.x;
    const int w = t >> 6, lane = t & 63, quad = lane >> 4, l16 = lane & 15;
    const int wr = (w >> 1) * 64, wc = (w & 1) * 64;

    const int s0 = w * 128 + lane;
    const int r0 = s0 & 127, kc0 = s0 >> 7;
    const int s1 = s0 + 64;
    const int r1 = s1 & 127, kc1 = s1 >> 7;
    const unsigned short* a0 = Xb + (size_t)(m0 + r0) * K_DIM + kc0 * 8;
    const unsigned short* a1 = Xb + (size_t)(m0 + r1) * K_DIM + kc1 * 8;
    const unsigned short* b0 = Wt + (size_t)(n0 + r0) * K_DIM + kc0 * 8;
    const unsigned short* b1 = Wt + (size_t)(n0 + r1) * K_DIM + kc1 * 8;

    f32x4 acc[4][4];
#pragma unroll
    for (int i = 0; i < 4; ++i)
#pragma unroll
        for (int j = 0; j < 4; ++j) acc[i][j] = (f32x4){0.f, 0.f, 0.f, 0.f};

    for (int k0 = 0; k0 < K_DIM; k0 += 32) {
        gll16(a0 + k0, &As[(w * 128) * 8]);
        gll16(a1 + k0, &As[(w * 128 + 64) * 8]);
        gll16(b0 + k0, &Bs[(w * 128) * 8]);
        gll16(b1 + k0, &Bs[(w * 128 + 64) * 8]);
        __syncthreads();
        bf16x8 af[4], bfr[4];
#pragma unroll
        for (int i = 0; i < 4; ++i)
            af[i] = *(const bf16x8*)&As[quad * 1024 + (wr + i * 16 + l16) * 8];
#pragma unroll
        for (int j = 0; j < 4; ++j)
            bfr[j] = *(const bf16x8*)&Bs[quad * 1024 + (wc + j * 16 + l16) * 8];
#pragma unroll
        for (int i = 0; i < 4; ++i)
#pragma unroll
            for (int j = 0; j < 4; ++j)
                acc[i][j] = __builtin_amdgcn_mfma_f32_16x16x32_bf16(af[i], bfr[j], acc[i][j], 0, 0, 0);
        __syncthreads();
    }

    // epilogue: bias; q scaled by 1/8; q,k -> [b,h][tok][d]; v -> TRANSPOSED [b,h][d][tok]
#pragma unroll
    for (int i = 0; i < 4; ++i) {
#pragma unroll
        for (int j = 0; j < 4; ++j) {
            int gn = n0 + wc + j * 16 + l16;
            int which = gn / 768;
            int rem = gn - which * 768;
            int hh = rem >> 6, dd = rem & 63;
            float bv = bias[gn];
#pragma unroll
            for (int r = 0; r < 4; ++r) {
                int gm = m0 + wr + i * 16 + quad * 4 + r;
                if (gm >= M_ROWS) continue;
                int bb = gm / 197;
                int tok = gm - bb * 197;
                float val = acc[i][j][r] + bv;
                if (which == 0) val *= 0.125f;
                size_t dst;
                if (which == 2)
                    dst = (size_t)2 * QSZ + ((size_t)((bb * 12 + hh) * 64 + dd)) * 208 + tok;
                else
                    dst = (size_t)which * QSZ + ((size_t)((bb * 12 + hh) * 197 + tok) * 64 + dd);
                qkv[dst] = f2bf(val);
            }
        }
    }
}

// ---------------- Kernel 3: attention, one WAVE per (q-tile, head, batch) ----------------
// No K/V staging, no barriers: K and Vt B-fragments are 16B/lane contiguous global reads
// served by L2. LDS only holds the per-wave P transpose (D-layout -> A-layout).
__global__ __launch_bounds__(64, 4) void attn_kernel(
        const unsigned short* __restrict__ qkv, float* __restrict__ out) {
    __shared__ __align__(16) unsigned short Ps[16 * 136];   // 4352 B

    const int tile = blockIdx.x, h = blockIdx.y, b = blockIdx.z;
    const int lane = threadIdx.x, quad = lane >> 4, l16 = lane & 15;

    const size_t headoff = (size_t)((b * 12 + h) * 197) * 64;
    const unsigned short* Qg  = qkv + headoff;
    const unsigned short* Kg  = qkv + (size_t)QSZ + headoff;
    const unsigned short* Vtg = qkv + (size_t)2 * QSZ + (size_t)((b * 12 + h) * 64) * 208;

    int rq = tile * 16 + l16;
    int tokq = rq < 197 ? rq : 196;
    bf16x8 aq0 = *(const bf16x8*)(Qg + (size_t)tokq * 64 + quad * 8);
    bf16x8 aq1 = *(const bf16x8*)(Qg + (size_t)tokq * 64 + 32 + quad * 8);

    // scores: 13 chunks of 16 kt-cols, K fragments straight from global
    f32x4 s[13];
#pragma unroll
    for (int c = 0; c < 13; ++c) {
        int krow = c * 16 + l16;
        if (krow > 196) krow = 196;                 // clamped read; masked below
        bf16x8 kb0 = *(const bf16x8*)(Kg + (size_t)krow * 64 + quad * 8);
        bf16x8 kb1 = *(const bf16x8*)(Kg + (size_t)krow * 64 + 32 + quad * 8);
        f32x4 zz = (f32x4){0.f, 0.f, 0.f, 0.f};
        zz = __builtin_amdgcn_mfma_f32_16x16x32_bf16(aq0, kb0, zz, 0, 0, 0);
        zz = __builtin_amdgcn_mfma_f32_16x16x32_bf16(aq1, kb1, zz, 0, 0, 0);
        s[c] = zz;
    }
    if (l16 >= 5) { s[12][0] = -1e30f; s[12][1] = -1e30f; s[12][2] = -1e30f; s[12][3] = -1e30f; }

    // softmax over 208 cols (rows = quad*4+r, cols spread over l16)
    float mx[4], lsum[4];
#pragma unroll
    for (int r = 0; r < 4; ++r) {
        float m = s[0][r];
#pragma unroll
        for (int c = 1; c < 13; ++c) m = fmaxf(m, s[c][r]);
#pragma unroll
        for (int d = 1; d < 16; d <<= 1) m = fmaxf(m, __shfl_xor(m, d));
        mx[r] = m;
        lsum[r] = 0.f;
    }
#pragma unroll
    for (int c = 0; c < 13; ++c)
#pragma unroll
        for (int r = 0; r < 4; ++r) {
            float p = __expf(s[c][r] - mx[r]);
            s[c][r] = p;
            lsum[r] += p;
        }
#pragma unroll
    for (int r = 0; r < 4; ++r)
#pragma unroll
        for (int d = 1; d < 16; d <<= 1) lsum[r] += __shfl_xor(lsum[r], d);

    f32x4 o[4];
#pragma unroll
    for (int j = 0; j < 4; ++j) o[j] = (f32x4){0.f, 0.f, 0.f, 0.f};

    // PV pass 1: P cols 0..127 (same-wave LDS round trip, no barrier needed)
#pragma unroll
    for (int c = 0; c < 8; ++c)
#pragma unroll
        for (int r = 0; r < 4; ++r)
            Ps[(quad * 4 + r) * 136 + c * 16 + l16] = f2bf(s[c][r]);
#pragma unroll
    for (int kc = 0; kc < 4; ++kc) {
        int kof = kc * 32 + quad * 8;
        bf16x8 ap = *(const bf16x8*)&Ps[l16 * 136 + kof];
#pragma unroll
        for (int j = 0; j < 4; ++j) {
            bf16x8 bv = *(const bf16x8*)(Vtg + (size_t)(j * 16 + l16) * 208 + kof);
            o[j] = __builtin_amdgcn_mfma_f32_16x16x32_bf16(ap, bv, o[j], 0, 0, 0);
        }
    }
    // PV pass 2: P cols 128..207 -> buffer cols 0..79; cols 80..95 zeroed
    // (kt 197..223 see p==0 exactly, so pad/poison V values contribute 0)
#pragma unroll
    for (int r = 0; r < 4; ++r)
        Ps[(quad * 4 + r) * 136 + 80 + l16] = 0;
#pragma unroll
    for (int c = 8; c < 13; ++c)
#pragma unroll
        for (int r = 0; r < 4; ++r)
            Ps[(quad * 4 + r) * 136 + (c - 8) * 16 + l16] = f2bf(s[c][r]);
#pragma unroll
    for (int kc = 0; kc < 3; ++kc) {
        int kof = kc * 32 + quad * 8;
        bf16x8 ap = *(const bf16x8*)&Ps[l16 * 136 + kof];
#pragma unroll
        for (int j = 0; j < 4; ++j) {
            bf16x8 bv = *(const bf16x8*)(Vtg + (size_t)(j * 16 + l16) * 208 + 128 + kof);
            o[j] = __builtin_amdgcn_mfma_f32_16x16x32_bf16(ap, bv, o[j], 0, 0, 0);
        }
    }

    // epilogue: divide by l, store fp32 [B, tok, 768]
    int tokbase = tile * 16 + quad * 4;
#pragma unroll
    for (int r = 0; r < 4; ++r) {
        int tr = tokbase + r;
        if (tr >= 197) continue;
        float inv = 1.f / lsum[r];
#pragma unroll
        for (int j = 0; j < 4; ++j)
            out[((size_t)(b * 197 + tr)) * 768 + h * 64 + j * 16 + l16] = o[j][r] * inv;
    }
}

extern "C" void kernel_launch(void* const* d_in, const int* in_sizes, int n_in,
                              void* d_out, int out_size, void* d_ws, size_t ws_size,
                              hipStream_t stream) {
    const float* X    = (const float*)d_in[0];   // [64,197,768]
    const float* W    = (const float*)d_in[1];   // [768,2304]
    const float* bias = (const float*)d_in[2];   // [2304]
    unsigned short* ws = (unsigned short*)d_ws;  // q | k | vt planes
    float* out = (float*)d_out;                  // [64,197,768]

    // Xb and Wt live in d_out's dead space (overwritten by attn at the end).
    unsigned short* Xb = (unsigned short*)d_out;
    unsigned short* Wt = (unsigned short*)d_out + XB_ELEMS;

    x2bf_kernel<<<4728, 256, 0, stream>>>(X, Xb);
    wtrans_kernel<<<dim3(72, 24), dim3(32, 8), 0, stream>>>(W, Wt);
    qkv_gemm_kernel<<<dim3(18, 99), 256, 0, stream>>>(Xb, Wt, bias, ws);
    attn_kernel<<<dim3(13, 12, 64), 64, 0, stream>>>(ws, out);
}

// Round 5
// 252.508 us; speedup vs baseline: 1.1039x; 1.1039x over previous
//
#include <hip/hip_runtime.h>

#define M_ROWS 12608          // 64*197
#define K_DIM  768
#define QSZ    9682944        // 64*12*197*64 elements per q/k/v plane
#define VT_OFF (3*QSZ)        // Vt plane offset in ws
#define XB_ELEMS 9732096      // 12672*768 bf16 X copy (lives in d_out scratch)

typedef __bf16 bf16x8 __attribute__((ext_vector_type(8)));
typedef float  f32x4  __attribute__((ext_vector_type(4)));

__device__ __forceinline__ unsigned short f2bf(float f) {
    unsigned u = __builtin_bit_cast(unsigned, f);
    u += 0x7fffu + ((u >> 16) & 1u);          // RNE, inputs are finite
    return (unsigned short)(u >> 16);
}

__device__ __forceinline__ void gll16(const unsigned short* g, unsigned short* l) {
    __builtin_amdgcn_global_load_lds(
        (const __attribute__((address_space(1))) unsigned int*)g,
        (__attribute__((address_space(3))) unsigned int*)l, 16, 0, 0);
}

// ---------------- Kernel 0: X fp32 -> bf16 (stored in d_out scratch area) ----------------
__global__ void x2bf_kernel(const float* __restrict__ X, unsigned short* __restrict__ Xb) {
    size_t base = ((size_t)blockIdx.x * 256 + threadIdx.x) * 8;
    float4 a = *(const float4*)(X + base);
    float4 b = *(const float4*)(X + base + 4);
    ushort4 lo, hi;
    lo.x = f2bf(a.x); lo.y = f2bf(a.y); lo.z = f2bf(a.z); lo.w = f2bf(a.w);
    hi.x = f2bf(b.x); hi.y = f2bf(b.y); hi.z = f2bf(b.z); hi.w = f2bf(b.w);
    *(ushort4*)(Xb + base) = lo;
    *(ushort4*)(Xb + base + 4) = hi;
}

// ---------------- Kernel 1: W [768,2304] fp32 -> Wt [2304,768] bf16 ----------------
__global__ void wtrans_kernel(const float* __restrict__ W, unsigned short* __restrict__ Wt) {
    __shared__ float tile[32][33];
    int n0 = blockIdx.x * 32, k0 = blockIdx.y * 32;
    int tx = threadIdx.x, ty = threadIdx.y;
#pragma unroll
    for (int i = 0; i < 4; ++i)
        tile[ty + i * 8][tx] = W[(size_t)(k0 + ty + i * 8) * 2304 + n0 + tx];
    __syncthreads();
#pragma unroll
    for (int i = 0; i < 4; ++i)
        Wt[(size_t)(n0 + ty + i * 8) * K_DIM + k0 + tx] = f2bf(tile[tx][ty + i * 8]);
}

// ---------------- Kernel 2: QKV GEMM, global_load_lds staging, k-major LDS ----------------
__global__ __launch_bounds__(256, 2) void qkv_gemm_kernel(
        const unsigned short* __restrict__ Xb, const unsigned short* __restrict__ Wt,
        const float* __restrict__ bias, unsigned short* __restrict__ qkv) {
    __shared__ __align__(16) unsigned short As[4096];   // 8 KB
    __shared__ __align__(16) unsigned short Bs[4096];   // 8 KB

    const int m0 = blockIdx.y * 128, n0 = blockIdx.x * 128;
    const int t = threadIdx.x;
    const int w = t >> 6, lane = t & 63, quad = lane >> 4, l16 = lane & 15;
    const int wr = (w >> 1) * 64, wc = (w & 1) * 64;

    const int s0 = w * 128 + lane;
    const int r0 = s0 & 127, kc0 = s0 >> 7;
    const int s1 = s0 + 64;
    const int r1 = s1 & 127, kc1 = s1 >> 7;
    const unsigned short* a0 = Xb + (size_t)(m0 + r0) * K_DIM + kc0 * 8;
    const unsigned short* a1 = Xb + (size_t)(m0 + r1) * K_DIM + kc1 * 8;
    const unsigned short* b0 = Wt + (size_t)(n0 + r0) * K_DIM + kc0 * 8;
    const unsigned short* b1 = Wt + (size_t)(n0 + r1) * K_DIM + kc1 * 8;

    f32x4 acc[4][4];
#pragma unroll
    for (int i = 0; i < 4; ++i)
#pragma unroll
        for (int j = 0; j < 4; ++j) acc[i][j] = (f32x4){0.f, 0.f, 0.f, 0.f};

    for (int k0 = 0; k0 < K_DIM; k0 += 32) {
        gll16(a0 + k0, &As[(w * 128) * 8]);
        gll16(a1 + k0, &As[(w * 128 + 64) * 8]);
        gll16(b0 + k0, &Bs[(w * 128) * 8]);
        gll16(b1 + k0, &Bs[(w * 128 + 64) * 8]);
        __syncthreads();
        bf16x8 af[4], bfr[4];
#pragma unroll
        for (int i = 0; i < 4; ++i)
            af[i] = *(const bf16x8*)&As[quad * 1024 + (wr + i * 16 + l16) * 8];
#pragma unroll
        for (int j = 0; j < 4; ++j)
            bfr[j] = *(const bf16x8*)&Bs[quad * 1024 + (wc + j * 16 + l16) * 8];
#pragma unroll
        for (int i = 0; i < 4; ++i)
#pragma unroll
            for (int j = 0; j < 4; ++j)
                acc[i][j] = __builtin_amdgcn_mfma_f32_16x16x32_bf16(af[i], bfr[j], acc[i][j], 0, 0, 0);
        __syncthreads();
    }

    // epilogue: bias; fold 1/8 into q; q,k,v all stored [b,h][tok][d] (coalesced)
#pragma unroll
    for (int i = 0; i < 4; ++i) {
#pragma unroll
        for (int j = 0; j < 4; ++j) {
            int gn = n0 + wc + j * 16 + l16;
            int which = gn / 768;
            int rem = gn - which * 768;
            int hh = rem >> 6, dd = rem & 63;
            float bv = bias[gn];
#pragma unroll
            for (int r = 0; r < 4; ++r) {
                int gm = m0 + wr + i * 16 + quad * 4 + r;
                if (gm >= M_ROWS) continue;
                int bb = gm / 197;
                int tok = gm - bb * 197;
                float val = acc[i][j][r] + bv;
                if (which == 0) val *= 0.125f;
                size_t dst = (size_t)which * QSZ +
                             ((size_t)((bb * 12 + hh) * 197 + tok) * 64 + dd);
                qkv[dst] = f2bf(val);
            }
        }
    }
}

// ---------------- Kernel 2b: V [g][tok][d] -> Vt [g][d][tok], stride 208, pad zeroed ----
__global__ __launch_bounds__(256) void vtrans_kernel(
        const unsigned short* __restrict__ qkv, unsigned short* __restrict__ vt) {
    __shared__ unsigned short T[64 * 210];   // stride 210 to break bank conflicts
    const int g = blockIdx.x;                // head index b*12+h
    const int t = threadIdx.x;
    const unsigned short* Vg = qkv + (size_t)2 * QSZ + (size_t)g * (197 * 64);
    unsigned short* Vtg = vt + (size_t)g * (64 * 208);

    // zero pad cols 197..207
    for (int idx = t; idx < 64 * 11; idx += 256) {
        int d = idx / 11, c = 197 + idx - d * 11;
        T[d * 210 + c] = 0;
    }
    // read V coalesced (16B chunks), write transposed into LDS
    for (int idx = t; idx < 197 * 8; idx += 256) {
        int tok = idx >> 3, d0 = (idx & 7) * 8;
        ushort4 v0 = *(const ushort4*)(Vg + (size_t)tok * 64 + d0);
        ushort4 v1 = *(const ushort4*)(Vg + (size_t)tok * 64 + d0 + 4);
        T[(d0 + 0) * 210 + tok] = v0.x;
        T[(d0 + 1) * 210 + tok] = v0.y;
        T[(d0 + 2) * 210 + tok] = v0.z;
        T[(d0 + 3) * 210 + tok] = v0.w;
        T[(d0 + 4) * 210 + tok] = v1.x;
        T[(d0 + 5) * 210 + tok] = v1.y;
        T[(d0 + 6) * 210 + tok] = v1.z;
        T[(d0 + 7) * 210 + tok] = v1.w;
    }
    __syncthreads();
    // write out coalesced: 64 rows x 208 elems = 1664 16B chunks
    for (int idx = t; idx < 1664; idx += 256) {
        int d = idx / 26, c8 = (idx - d * 26) * 8;
        ushort4 o0, o1;
        o0.x = T[d * 210 + c8 + 0]; o0.y = T[d * 210 + c8 + 1];
        o0.z = T[d * 210 + c8 + 2]; o0.w = T[d * 210 + c8 + 3];
        o1.x = T[d * 210 + c8 + 4]; o1.y = T[d * 210 + c8 + 5];
        o1.z = T[d * 210 + c8 + 6]; o1.w = T[d * 210 + c8 + 7];
        *(ushort4*)(Vtg + (size_t)d * 208 + c8) = o0;
        *(ushort4*)(Vtg + (size_t)d * 208 + c8 + 4) = o1;
    }
}

// ---------------- Kernel 3: attention, one WAVE per (q-tile, head); XCD-swizzled ----------
__global__ __launch_bounds__(64, 4) void attn_kernel(
        const unsigned short* __restrict__ qkv, float* __restrict__ out) {
    __shared__ __align__(16) unsigned short Ps[16 * 136];   // 4352 B

    // XCD-aware decode: blocks dispatch round-robin to 8 XCDs by linear id;
    // give all 13 tiles of head g to XCD g%8 so K/V stay in one L2.
    const int bid = blockIdx.x;
    const int xcd = bid & 7;
    const int slot = bid >> 3;            // 0..1247
    const int tile = slot % 13;
    const int g = xcd + 8 * (slot / 13);  // 0..767
    const int b = g / 12, h = g - b * 12;

    const int lane = threadIdx.x, quad = lane >> 4, l16 = lane & 15;

    const size_t headoff = (size_t)(g * 197) * 64;
    const unsigned short* Qg  = qkv + headoff;
    const unsigned short* Kg  = qkv + (size_t)QSZ + headoff;
    const unsigned short* Vtg = qkv + (size_t)VT_OFF + (size_t)g * (64 * 208);

    int rq = tile * 16 + l16;
    int tokq = rq < 197 ? rq : 196;
    bf16x8 aq0 = *(const bf16x8*)(Qg + (size_t)tokq * 64 + quad * 8);
    bf16x8 aq1 = *(const bf16x8*)(Qg + (size_t)tokq * 64 + 32 + quad * 8);

    // scores: 13 chunks of 16 kt-cols, K fragments straight from global/L2
    f32x4 s[13];
#pragma unroll
    for (int c = 0; c < 13; ++c) {
        int krow = c * 16 + l16;
        if (krow > 196) krow = 196;                 // clamped read; masked below
        bf16x8 kb0 = *(const bf16x8*)(Kg + (size_t)krow * 64 + quad * 8);
        bf16x8 kb1 = *(const bf16x8*)(Kg + (size_t)krow * 64 + 32 + quad * 8);
        f32x4 zz = (f32x4){0.f, 0.f, 0.f, 0.f};
        zz = __builtin_amdgcn_mfma_f32_16x16x32_bf16(aq0, kb0, zz, 0, 0, 0);
        zz = __builtin_amdgcn_mfma_f32_16x16x32_bf16(aq1, kb1, zz, 0, 0, 0);
        s[c] = zz;
    }
    if (l16 >= 5) { s[12][0] = -1e30f; s[12][1] = -1e30f; s[12][2] = -1e30f; s[12][3] = -1e30f; }

    // softmax over 208 cols (rows = quad*4+r, cols spread over l16)
    float mx[4], lsum[4];
#pragma unroll
    for (int r = 0; r < 4; ++r) {
        float m = s[0][r];
#pragma unroll
        for (int c = 1; c < 13; ++c) m = fmaxf(m, s[c][r]);
#pragma unroll
        for (int d = 1; d < 16; d <<= 1) m = fmaxf(m, __shfl_xor(m, d));
        mx[r] = m;
        lsum[r] = 0.f;
    }
#pragma unroll
    for (int c = 0; c < 13; ++c)
#pragma unroll
        for (int r = 0; r < 4; ++r) {
            float p = __expf(s[c][r] - mx[r]);
            s[c][r] = p;
            lsum[r] += p;
        }
#pragma unroll
    for (int r = 0; r < 4; ++r)
#pragma unroll
        for (int d = 1; d < 16; d <<= 1) lsum[r] += __shfl_xor(lsum[r], d);

    f32x4 o[4];
#pragma unroll
    for (int j = 0; j < 4; ++j) o[j] = (f32x4){0.f, 0.f, 0.f, 0.f};

    // PV pass 1: P cols 0..127 (same-wave LDS round trip, no barrier needed)
#pragma unroll
    for (int c = 0; c < 8; ++c)
#pragma unroll
        for (int r = 0; r < 4; ++r)
            Ps[(quad * 4 + r) * 136 + c * 16 + l16] = f2bf(s[c][r]);
#pragma unroll
    for (int kc = 0; kc < 4; ++kc) {
        int kof = kc * 32 + quad * 8;
        bf16x8 ap = *(const bf16x8*)&Ps[l16 * 136 + kof];
#pragma unroll
        for (int j = 0; j < 4; ++j) {
            bf16x8 bv = *(const bf16x8*)(Vtg + (size_t)(j * 16 + l16) * 208 + kof);
            o[j] = __builtin_amdgcn_mfma_f32_16x16x32_bf16(ap, bv, o[j], 0, 0, 0);
        }
    }
    // PV pass 2: P cols 128..207 -> buffer cols 0..79; cols 80..95 zeroed (p==0)
#pragma unroll
    for (int r = 0; r < 4; ++r)
        Ps[(quad * 4 + r) * 136 + 80 + l16] = 0;
#pragma unroll
    for (int c = 8; c < 13; ++c)
#pragma unroll
        for (int r = 0; r < 4; ++r)
            Ps[(quad * 4 + r) * 136 + (c - 8) * 16 + l16] = f2bf(s[c][r]);
#pragma unroll
    for (int kc = 0; kc < 3; ++kc) {
        int kofA = kc * 32 + quad * 8;
        // kc==2, quad>=2 covers kt 208..223 where p==0: clamp B-read inside the row
        int kofB = (kc == 2 && quad >= 2) ? 0 : kofA;
        bf16x8 ap = *(const bf16x8*)&Ps[l16 * 136 + kofA];
#pragma unroll
        for (int j = 0; j < 4; ++j) {
            bf16x8 bv = *(const bf16x8*)(Vtg + (size_t)(j * 16 + l16) * 208 + 128 + kofB);
            o[j] = __builtin_amdgcn_mfma_f32_16x16x32_bf16(ap, bv, o[j], 0, 0, 0);
        }
    }

    // epilogue: divide by l, store fp32 [B, tok, 768]
    int tokbase = tile * 16 + quad * 4;
#pragma unroll
    for (int r = 0; r < 4; ++r) {
        int tr = tokbase + r;
        if (tr >= 197) continue;
        float inv = 1.f / lsum[r];
#pragma unroll
        for (int j = 0; j < 4; ++j)
            out[((size_t)(b * 197 + tr)) * 768 + h * 64 + j * 16 + l16] = o[j][r] * inv;
    }
}

extern "C" void kernel_launch(void* const* d_in, const int* in_sizes, int n_in,
                              void* d_out, int out_size, void* d_ws, size_t ws_size,
                              hipStream_t stream) {
    const float* X    = (const float*)d_in[0];   // [64,197,768]
    const float* W    = (const float*)d_in[1];   // [768,2304]
    const float* bias = (const float*)d_in[2];   // [2304]
    unsigned short* ws = (unsigned short*)d_ws;  // q | k | v | vt planes
    float* out = (float*)d_out;                  // [64,197,768]

    // Xb and Wt live in d_out's dead space (overwritten by attn at the end).
    unsigned short* Xb = (unsigned short*)d_out;
    unsigned short* Wt = (unsigned short*)d_out + XB_ELEMS;

    x2bf_kernel<<<4728, 256, 0, stream>>>(X, Xb);
    wtrans_kernel<<<dim3(72, 24), dim3(32, 8), 0, stream>>>(W, Wt);
    qkv_gemm_kernel<<<dim3(18, 99), 256, 0, stream>>>(Xb, Wt, bias, ws);
    vtrans_kernel<<<768, 256, 0, stream>>>(ws, ws + VT_OFF);
    attn_kernel<<<9984, 64, 0, stream>>>(ws, out);
}

// Round 6
// 231.414 us; speedup vs baseline: 1.2045x; 1.0912x over previous
//
#include <hip/hip_runtime.h>

#define M_ROWS 12608          // 64*197
#define K_DIM  768
#define QSZ    9682944        // 64*12*197*64 elements per q/k/v plane
#define XB_ELEMS 9732096      // 12672*768 bf16 X copy (lives in d_out scratch)

typedef __bf16 bf16x8 __attribute__((ext_vector_type(8)));
typedef float  f32x4  __attribute__((ext_vector_type(4)));

__device__ __forceinline__ unsigned short f2bf(float f) {
    unsigned u = __builtin_bit_cast(unsigned, f);
    u += 0x7fffu + ((u >> 16) & 1u);          // RNE, inputs are finite
    return (unsigned short)(u >> 16);
}

__device__ __forceinline__ void gll16(const unsigned short* g, unsigned short* l) {
    __builtin_amdgcn_global_load_lds(
        (const __attribute__((address_space(1))) unsigned int*)g,
        (__attribute__((address_space(3))) unsigned int*)l, 16, 0, 0);
}

// ---------------- Kernel 0: X fp32 -> bf16 (stored in d_out scratch area) ----------------
__global__ void x2bf_kernel(const float* __restrict__ X, unsigned short* __restrict__ Xb) {
    size_t base = ((size_t)blockIdx.x * 256 + threadIdx.x) * 8;
    float4 a = *(const float4*)(X + base);
    float4 b = *(const float4*)(X + base + 4);
    ushort4 lo, hi;
    lo.x = f2bf(a.x); lo.y = f2bf(a.y); lo.z = f2bf(a.z); lo.w = f2bf(a.w);
    hi.x = f2bf(b.x); hi.y = f2bf(b.y); hi.z = f2bf(b.z); hi.w = f2bf(b.w);
    *(ushort4*)(Xb + base) = lo;
    *(ushort4*)(Xb + base + 4) = hi;
}

// ---------------- Kernel 1: W [768,2304] fp32 -> Wt [2304,768] bf16 ----------------
__global__ void wtrans_kernel(const float* __restrict__ W, unsigned short* __restrict__ Wt) {
    __shared__ float tile[32][33];
    int n0 = blockIdx.x * 32, k0 = blockIdx.y * 32;
    int tx = threadIdx.x, ty = threadIdx.y;
#pragma unroll
    for (int i = 0; i < 4; ++i)
        tile[ty + i * 8][tx] = W[(size_t)(k0 + ty + i * 8) * 2304 + n0 + tx];
    __syncthreads();
#pragma unroll
    for (int i = 0; i < 4; ++i)
        Wt[(size_t)(n0 + ty + i * 8) * K_DIM + k0 + tx] = f2bf(tile[tx][ty + i * 8]);
}

// ---------------- Kernel 2: QKV GEMM, global_load_lds staging, k-major LDS ----------------
__global__ __launch_bounds__(256, 2) void qkv_gemm_kernel(
        const unsigned short* __restrict__ Xb, const unsigned short* __restrict__ Wt,
        const float* __restrict__ bias, unsigned short* __restrict__ qkv) {
    __shared__ __align__(16) unsigned short As[4096];   // 8 KB
    __shared__ __align__(16) unsigned short Bs[4096];   // 8 KB

    const int m0 = blockIdx.y * 128, n0 = blockIdx.x * 128;
    const int t = threadIdx.x;
    const int w = t >> 6, lane = t & 63, quad = lane >> 4, l16 = lane & 15;
    const int wr = (w >> 1) * 64, wc = (w & 1) * 64;

    const int s0 = w * 128 + lane;
    const int r0 = s0 & 127, kc0 = s0 >> 7;
    const int s1 = s0 + 64;
    const int r1 = s1 & 127, kc1 = s1 >> 7;
    const unsigned short* a0 = Xb + (size_t)(m0 + r0) * K_DIM + kc0 * 8;
    const unsigned short* a1 = Xb + (size_t)(m0 + r1) * K_DIM + kc1 * 8;
    const unsigned short* b0 = Wt + (size_t)(n0 + r0) * K_DIM + kc0 * 8;
    const unsigned short* b1 = Wt + (size_t)(n0 + r1) * K_DIM + kc1 * 8;

    f32x4 acc[4][4];
#pragma unroll
    for (int i = 0; i < 4; ++i)
#pragma unroll
        for (int j = 0; j < 4; ++j) acc[i][j] = (f32x4){0.f, 0.f, 0.f, 0.f};

    for (int k0 = 0; k0 < K_DIM; k0 += 32) {
        gll16(a0 + k0, &As[(w * 128) * 8]);
        gll16(a1 + k0, &As[(w * 128 + 64) * 8]);
        gll16(b0 + k0, &Bs[(w * 128) * 8]);
        gll16(b1 + k0, &Bs[(w * 128 + 64) * 8]);
        __syncthreads();
        bf16x8 af[4], bfr[4];
#pragma unroll
        for (int i = 0; i < 4; ++i)
            af[i] = *(const bf16x8*)&As[quad * 1024 + (wr + i * 16 + l16) * 8];
#pragma unroll
        for (int j = 0; j < 4; ++j)
            bfr[j] = *(const bf16x8*)&Bs[quad * 1024 + (wc + j * 16 + l16) * 8];
#pragma unroll
        for (int i = 0; i < 4; ++i)
#pragma unroll
            for (int j = 0; j < 4; ++j)
                acc[i][j] = __builtin_amdgcn_mfma_f32_16x16x32_bf16(af[i], bfr[j], acc[i][j], 0, 0, 0);
        __syncthreads();
    }

    // epilogue: bias; fold 1/8 into q; q,k,v all stored [b,h][tok][d] (coalesced)
#pragma unroll
    for (int i = 0; i < 4; ++i) {
#pragma unroll
        for (int j = 0; j < 4; ++j) {
            int gn = n0 + wc + j * 16 + l16;
            int which = gn / 768;
            int rem = gn - which * 768;
            int hh = rem >> 6, dd = rem & 63;
            float bv = bias[gn];
#pragma unroll
            for (int r = 0; r < 4; ++r) {
                int gm = m0 + wr + i * 16 + quad * 4 + r;
                if (gm >= M_ROWS) continue;
                int bb = gm / 197;
                int tok = gm - bb * 197;
                float val = acc[i][j][r] + bv;
                if (which == 0) val *= 0.125f;
                size_t dst = (size_t)which * QSZ +
                             ((size_t)((bb * 12 + hh) * 197 + tok) * 64 + dd);
                qkv[dst] = f2bf(val);
            }
        }
    }
}

// ---------------- Kernel 3: attention, one block per head; K + V^T staged in LDS ----------
__global__ __launch_bounds__(256, 2) void attn_kernel(
        const unsigned short* __restrict__ qkv, float* __restrict__ out) {
    __shared__ __align__(16) unsigned short Ks[197 * 72];     // 28368 B
    __shared__ __align__(16) unsigned short Vt[64 * 216];     // 27648 B (stride 216: 2-way banks)
    __shared__ __align__(16) unsigned short Ps[4 * 16 * 136]; // 17408 B

    const int g = blockIdx.x;            // head index b*12+h
    const int b = g / 12, h = g - b * 12;
    const int t = threadIdx.x, w = t >> 6, lane = t & 63;
    const int quad = lane >> 4, l16 = lane & 15;

    const size_t headoff = (size_t)(g * 197) * 64;
    const unsigned short* Qg = qkv + headoff;
    const unsigned short* Kg = qkv + (size_t)QSZ + headoff;
    const unsigned short* Vg = qkv + (size_t)2 * QSZ + headoff;

    // stage K coalesced: 197 rows x 64 d, 16B chunks
    for (int idx = t; idx < 1576; idx += 256) {
        int row = idx >> 3, c8 = (idx & 7) * 8;
        *(uint4*)&Ks[row * 72 + c8] = *(const uint4*)(Kg + (size_t)row * 64 + c8);
    }
    // zero Vt pad cols 197..215 (PV reads them where p==0; avoid NaN*0)
    for (int idx = t; idx < 64 * 19; idx += 256) {
        int d = idx / 19, c = 197 + idx - d * 19;
        Vt[d * 216 + c] = 0;
    }
    // stage V transposed: coalesced 16B global read, scalar LDS scatter
    for (int idx = t; idx < 1576; idx += 256) {
        int tok = idx >> 3, d0 = (idx & 7) * 8;
        ushort4 v0 = *(const ushort4*)(Vg + (size_t)tok * 64 + d0);
        ushort4 v1 = *(const ushort4*)(Vg + (size_t)tok * 64 + d0 + 4);
        Vt[(d0 + 0) * 216 + tok] = v0.x;
        Vt[(d0 + 1) * 216 + tok] = v0.y;
        Vt[(d0 + 2) * 216 + tok] = v0.z;
        Vt[(d0 + 3) * 216 + tok] = v0.w;
        Vt[(d0 + 4) * 216 + tok] = v1.x;
        Vt[(d0 + 5) * 216 + tok] = v1.y;
        Vt[(d0 + 6) * 216 + tok] = v1.z;
        Vt[(d0 + 7) * 216 + tok] = v1.w;
    }
    __syncthreads();

    unsigned short* Pw = Ps + w * (16 * 136);

    // wave w handles q-tiles w, w+4, w+8, w+12 (13 tiles of 16 rows)
    for (int tile = w; tile < 13; tile += 4) {
        int rq = tile * 16 + l16;
        int tokq = rq < 197 ? rq : 196;
        bf16x8 aq0 = *(const bf16x8*)(Qg + (size_t)tokq * 64 + quad * 8);
        bf16x8 aq1 = *(const bf16x8*)(Qg + (size_t)tokq * 64 + 32 + quad * 8);

        // scores: 13 chunks of 16 kt-cols, K fragments from LDS
        f32x4 s[13];
#pragma unroll
        for (int c = 0; c < 13; ++c) {
            int krow = c * 16 + l16;
            if (krow > 196) krow = 196;             // clamped read; masked below
            bf16x8 kb0 = *(const bf16x8*)&Ks[krow * 72 + quad * 8];
            bf16x8 kb1 = *(const bf16x8*)&Ks[krow * 72 + 32 + quad * 8];
            f32x4 zz = (f32x4){0.f, 0.f, 0.f, 0.f};
            zz = __builtin_amdgcn_mfma_f32_16x16x32_bf16(aq0, kb0, zz, 0, 0, 0);
            zz = __builtin_amdgcn_mfma_f32_16x16x32_bf16(aq1, kb1, zz, 0, 0, 0);
            s[c] = zz;
        }
        if (l16 >= 5) { s[12][0] = -1e30f; s[12][1] = -1e30f; s[12][2] = -1e30f; s[12][3] = -1e30f; }

        // softmax over 208 cols (rows = quad*4+r, cols spread over l16)
        float mx[4], lsum[4];
#pragma unroll
        for (int r = 0; r < 4; ++r) {
            float m = s[0][r];
#pragma unroll
            for (int c = 1; c < 13; ++c) m = fmaxf(m, s[c][r]);
#pragma unroll
            for (int d = 1; d < 16; d <<= 1) m = fmaxf(m, __shfl_xor(m, d));
            mx[r] = m;
            lsum[r] = 0.f;
        }
#pragma unroll
        for (int c = 0; c < 13; ++c)
#pragma unroll
            for (int r = 0; r < 4; ++r) {
                float p = __expf(s[c][r] - mx[r]);
                s[c][r] = p;
                lsum[r] += p;
            }
#pragma unroll
        for (int r = 0; r < 4; ++r)
#pragma unroll
            for (int d = 1; d < 16; d <<= 1) lsum[r] += __shfl_xor(lsum[r], d);

        f32x4 o[4];
#pragma unroll
        for (int j = 0; j < 4; ++j) o[j] = (f32x4){0.f, 0.f, 0.f, 0.f};

        // PV pass 1: P cols 0..127 (same-wave LDS round trip, no barrier)
#pragma unroll
        for (int c = 0; c < 8; ++c)
#pragma unroll
            for (int r = 0; r < 4; ++r)
                Pw[(quad * 4 + r) * 136 + c * 16 + l16] = f2bf(s[c][r]);
#pragma unroll
        for (int kc = 0; kc < 4; ++kc) {
            int kof = kc * 32 + quad * 8;
            bf16x8 ap = *(const bf16x8*)&Pw[l16 * 136 + kof];
#pragma unroll
            for (int j = 0; j < 4; ++j) {
                bf16x8 bv = *(const bf16x8*)&Vt[(j * 16 + l16) * 216 + kof];
                o[j] = __builtin_amdgcn_mfma_f32_16x16x32_bf16(ap, bv, o[j], 0, 0, 0);
            }
        }
        // PV pass 2: P cols 128..207 -> buffer cols 0..79; cols 80..95 zeroed (p==0)
#pragma unroll
        for (int r = 0; r < 4; ++r)
            Pw[(quad * 4 + r) * 136 + 80 + l16] = 0;
#pragma unroll
        for (int c = 8; c < 13; ++c)
#pragma unroll
            for (int r = 0; r < 4; ++r)
                Pw[(quad * 4 + r) * 136 + (c - 8) * 16 + l16] = f2bf(s[c][r]);
#pragma unroll
        for (int kc = 0; kc < 3; ++kc) {
            int kofA = kc * 32 + quad * 8;
            // kc==2, quad>=2 -> kt 208..223 where p==0 exactly; clamp LDS read in-range
            int kofB = (kc == 2 && quad >= 2) ? 0 : kofA;
            bf16x8 ap = *(const bf16x8*)&Pw[l16 * 136 + kofA];
#pragma unroll
            for (int j = 0; j < 4; ++j) {
                bf16x8 bv = *(const bf16x8*)&Vt[(j * 16 + l16) * 216 + 128 + kofB];
                o[j] = __builtin_amdgcn_mfma_f32_16x16x32_bf16(ap, bv, o[j], 0, 0, 0);
            }
        }

        // epilogue: divide by l, store fp32 [B, tok, 768]
        int tokbase = tile * 16 + quad * 4;
#pragma unroll
        for (int r = 0; r < 4; ++r) {
            int tr = tokbase + r;
            if (tr >= 197) continue;
            float inv = 1.f / lsum[r];
#pragma unroll
            for (int j = 0; j < 4; ++j)
                out[((size_t)(b * 197 + tr)) * 768 + h * 64 + j * 16 + l16] = o[j][r] * inv;
        }
    }
}

extern "C" void kernel_launch(void* const* d_in, const int* in_sizes, int n_in,
                              void* d_out, int out_size, void* d_ws, size_t ws_size,
                              hipStream_t stream) {
    const float* X    = (const float*)d_in[0];   // [64,197,768]
    const float* W    = (const float*)d_in[1];   // [768,2304]
    const float* bias = (const float*)d_in[2];   // [2304]
    unsigned short* ws = (unsigned short*)d_ws;  // q | k | v planes
    float* out = (float*)d_out;                  // [64,197,768]

    // Xb and Wt live in d_out's dead space (overwritten by attn at the end).
    unsigned short* Xb = (unsigned short*)d_out;
    unsigned short* Wt = (unsigned short*)d_out + XB_ELEMS;

    x2bf_kernel<<<4728, 256, 0, stream>>>(X, Xb);
    wtrans_kernel<<<dim3(72, 24), dim3(32, 8), 0, stream>>>(W, Wt);
    qkv_gemm_kernel<<<dim3(18, 99), 256, 0, stream>>>(Xb, Wt, bias, ws);
    attn_kernel<<<768, 256, 0, stream>>>(ws, out);
}